// Round 1
// 863.018 us; speedup vs baseline: 1.4530x; 1.4530x over previous
//
#include <hip/hip_runtime.h>
#include <hip/hip_bf16.h>
#include <math.h>

// Problem constants (B=4, T=1024, H=1024, V=32000)
constexpr int kH   = 1024;
constexpr int kV   = 32000;
constexpr int kTok = 4096;    // B*T
constexpr int BM   = 256;
constexpr int BN   = 256;
constexpr int BK   = 64;      // f16 elements per K-step
constexpr int NT   = kH / BK;    // 16 K-tiles
constexpr int NVT  = kV / BN;    // 125
constexpr int NMT  = kTok / BM;  // 16

typedef _Float16 f16x8 __attribute__((ext_vector_type(8)));
typedef float    f32x4 __attribute__((ext_vector_type(4)));

typedef __attribute__((address_space(1))) const void gvoid_t;
typedef __attribute__((address_space(3))) void lvoid_t;

// fp32 -> f16 with XOR-swizzled 16B blocks: within each 64-elem K-chunk,
// logical block c of row r lands at physical block c ^ (r & 7). GEMM staging
// stays linear (global_load_lds requirement) while ds_read_b128 fragment reads
// spread across bank groups (measured 0 conflicts).
__global__ __launch_bounds__(256) void convert_kernel(
    const float* __restrict__ src, _Float16* __restrict__ dst)
{
  int idx = blockIdx.x * 256 + threadIdx.x;   // one 8-elem block per thread
  int row = idx >> 7;                          // kH/8 = 128 blocks per row
  int blk = idx & 127;
  int chunk = blk >> 3;                        // 64-elem chunk (16 per row)
  int c = blk & 7;
  int p = c ^ (row & 7);
  const float* s = src + ((size_t)row << 10) + (blk << 3);
  float4 v0 = *(const float4*)s;
  float4 v1 = *(const float4*)(s + 4);
  f16x8 o = { (_Float16)v0.x, (_Float16)v0.y, (_Float16)v0.z, (_Float16)v0.w,
              (_Float16)v1.x, (_Float16)v1.y, (_Float16)v1.z, (_Float16)v1.w };
  *(f16x8*)&dst[((size_t)row << 10) + (chunk << 6) + (p << 3)] = o;
}

// ---------------------------------------------------------------------------
// Fused GEMM + per-row (max, sum-exp) partials over each 256-col vocab tile.
// 256x256 tile, BK=64, 8 waves (2M x 4N), per-wave output 128 tok x 64 voc.
// 4 phases per K-tile (counted-vmcnt pipeline, 3 half-tiles in flight):
//   phase g: ds_read A rows [g*32,g*32+32) (+ all B at g==0); issue one
//   half-tile global_load_lds into the region that died last phase;
//   s_barrier; MFMA x16 under setprio(1); s_barrier.
// vmcnt(6) once per K-tile (at g==3) -> tile t+1 guaranteed complete, 3
// half-tiles of t+2 still in flight across the barrier.
// MFMA operands SWAPPED (mfma(b,a)): output row = vocab, col = token, so the
// per-token reduction is 16 register-local values + 2-step cross-quad shuffle.
// ---------------------------------------------------------------------------
__global__ __launch_bounds__(512, 2) void lse_gemm_kernel(
    const _Float16* __restrict__ X0, const _Float16* __restrict__ W0,
    const _Float16* __restrict__ X1, const _Float16* __restrict__ W1,
    float2* __restrict__ P0, float2* __restrict__ P1)
{
  __shared__ _Float16 lds[2][2][BM * BK];   // [buf][A=0/B=1][256*64] = 128 KB

  const _Float16* Xp = blockIdx.z ? X1 : X0;
  const _Float16* Wp = blockIdx.z ? W1 : W0;
  float2* Pp = blockIdx.z ? P1 : P0;

  const int tid  = threadIdx.x;
  const int wave = tid >> 6;
  const int lane = tid & 63;
  const int quad = lane >> 4;
  const int lc   = lane & 15;
  const int wr   = wave >> 2;   // 0..1 : token half  (128 rows)
  const int wc   = wave & 3;    // 0..3 : vocab quarter (64 rows)
  const int srow = lane >> 3;   // staging row within 8-row group
  const int sblk = lane & 7;    // staging 16B block within row chunk

  const int m_base = blockIdx.x * BM;
  const int v_base = blockIdx.y * BN;

  // Staging base pointers: each load covers 8 rows x 128B (one wave = 1KB).
  const _Float16* gA = Xp + (size_t)(m_base + wave * 8 + srow) * kH + sblk * 8;
  const _Float16* gB = Wp + (size_t)(v_base + wave * 8 + srow) * kH + sblk * 8;

  // Fragment offsets: row & 7 == lc & 7 for every fragment row, so the XOR
  // de-swizzle term is row-independent.
  const int xb0 = ((quad       ^ (lc & 7)) << 3);   // K-half 0
  const int xb1 = (((quad + 4) ^ (lc & 7)) << 3);   // K-half 1
  const int rA0 = (wr * 128 + lc) * BK;             // + g*2048 + i*1024 + xb
  const int rB0 = (wc * 64  + lc) * BK;             // + j*1024 + xb

  f32x4 acc[8][4];
#pragma unroll
  for (int i = 0; i < 8; ++i)
#pragma unroll
    for (int j = 0; j < 4; ++j) acc[i][j] = (f32x4){0.f, 0.f, 0.f, 0.f};

  f16x8 bf[4][2];   // B fragments, persist across the 4 phases of a K-tile

// Stage one half-tile (128 rows x 64 f16) of A or B for K-tile kt into buf c.
// 2 x global_load_lds per thread; LDS dest is wave-uniform + lane*16B (HW).
#define STG_A(c, kt, h) do {                                                        \
    __builtin_amdgcn_global_load_lds(                                               \
        (gvoid_t*)(gA + (size_t)((h) * 128     ) * kH + (kt) * BK),                 \
        (lvoid_t*)&lds[c][0][(((h) * 128     ) + wave * 8) * BK], 16, 0, 0);        \
    __builtin_amdgcn_global_load_lds(                                               \
        (gvoid_t*)(gA + (size_t)((h) * 128 + 64) * kH + (kt) * BK),                 \
        (lvoid_t*)&lds[c][0][(((h) * 128 + 64) + wave * 8) * BK], 16, 0, 0);        \
  } while (0)
#define STG_B(c, kt, h) do {                                                        \
    __builtin_amdgcn_global_load_lds(                                               \
        (gvoid_t*)(gB + (size_t)((h) * 128     ) * kH + (kt) * BK),                 \
        (lvoid_t*)&lds[c][1][(((h) * 128     ) + wave * 8) * BK], 16, 0, 0);        \
    __builtin_amdgcn_global_load_lds(                                               \
        (gvoid_t*)(gB + (size_t)((h) * 128 + 64) * kH + (kt) * BK),                 \
        (lvoid_t*)&lds[c][1][(((h) * 128 + 64) + wave * 8) * BK], 16, 0, 0);        \
  } while (0)

#define VM6  asm volatile("s_waitcnt vmcnt(6)" ::: "memory")
#define VM0  asm volatile("s_waitcnt vmcnt(0)" ::: "memory")
#define NOP_ ((void)0)

// One phase: ds_reads -> stage -> barrier -> MFMA cluster -> barrier.
#define PH(c, g, S, V) do {                                                         \
    if ((g) == 0) {                                                                 \
      _Pragma("unroll")                                                             \
      for (int j = 0; j < 4; ++j) {                                                 \
        bf[j][0] = *(const f16x8*)&lds[c][1][rB0 + j * 1024 + xb0];                 \
        bf[j][1] = *(const f16x8*)&lds[c][1][rB0 + j * 1024 + xb1];                 \
      }                                                                             \
    }                                                                               \
    f16x8 a00 = *(const f16x8*)&lds[c][0][rA0 + (g) * 2048 +        xb0];           \
    f16x8 a01 = *(const f16x8*)&lds[c][0][rA0 + (g) * 2048 +        xb1];           \
    f16x8 a10 = *(const f16x8*)&lds[c][0][rA0 + (g) * 2048 + 1024 + xb0];           \
    f16x8 a11 = *(const f16x8*)&lds[c][0][rA0 + (g) * 2048 + 1024 + xb1];           \
    S;                                                                              \
    V;                                                                              \
    __builtin_amdgcn_s_barrier();                                                   \
    __builtin_amdgcn_s_setprio(1);                                                  \
    _Pragma("unroll")                                                               \
    for (int j = 0; j < 4; ++j) {                                                   \
      acc[(g)*2  ][j] = __builtin_amdgcn_mfma_f32_16x16x32_f16(bf[j][0], a00, acc[(g)*2  ][j], 0, 0, 0); \
      acc[(g)*2  ][j] = __builtin_amdgcn_mfma_f32_16x16x32_f16(bf[j][1], a01, acc[(g)*2  ][j], 0, 0, 0); \
      acc[(g)*2+1][j] = __builtin_amdgcn_mfma_f32_16x16x32_f16(bf[j][0], a10, acc[(g)*2+1][j], 0, 0, 0); \
      acc[(g)*2+1][j] = __builtin_amdgcn_mfma_f32_16x16x32_f16(bf[j][1], a11, acc[(g)*2+1][j], 0, 0, 0); \
    }                                                                               \
    __builtin_amdgcn_s_setprio(0);                                                  \
    __builtin_amdgcn_s_barrier();                                                   \
  } while (0)

  // Prologue: tile0 complete (buf0) + tile1 B0,B1,A0 (buf1) = 7 half-tiles.
  STG_B(0, 0, 0); STG_B(0, 0, 1); STG_A(0, 0, 0); STG_A(0, 0, 1);
  STG_B(1, 1, 0); STG_B(1, 1, 1); STG_A(1, 1, 0);
  VM6;                               // tile0 landed; tile1's 3 in flight
  __builtin_amdgcn_s_barrier();

  // Steady state: while computing tile kt, stage (kt+1).A1 then (kt+2).B0/B1/A0
  // into the regions consumed 1+ phases ago.
  for (int kt = 0; kt < NT - 2; kt += 2) {
    PH(0, 0, STG_A(1, kt + 1, 1), NOP_);
    PH(0, 1, STG_B(0, kt + 2, 0), NOP_);
    PH(0, 2, STG_B(0, kt + 2, 1), NOP_);
    PH(0, 3, STG_A(0, kt + 2, 0), VM6);   // tile kt+1 complete
    PH(1, 0, STG_A(0, kt + 2, 1), NOP_);
    PH(1, 1, STG_B(1, kt + 3, 0), NOP_);
    PH(1, 2, STG_B(1, kt + 3, 1), NOP_);
    PH(1, 3, STG_A(1, kt + 3, 0), VM6);   // tile kt+2 complete
  }
  // Tail: tiles NT-2 (buf0) and NT-1 (buf1); drain to 0 once.
  PH(0, 0, STG_A(1, NT - 1, 1), NOP_);
  PH(0, 1, NOP_, NOP_);
  PH(0, 2, NOP_, NOP_);
  PH(0, 3, NOP_, VM0);                    // tile NT-1 complete
  PH(1, 0, NOP_, NOP_);
  PH(1, 1, NOP_, NOP_);
  PH(1, 2, NOP_, NOP_);
  PH(1, 3, NOP_, NOP_);

#undef PH
#undef STG_A
#undef STG_B

  // Epilogue. acc[f][j][r] = logits[token = wr*128 + f*16 + lc]
  //                                [vocab = v_base + wc*64 + j*16 + quad*4 + r]
  // Per token: 16 register-local values, then combine across the 4 quads.
  float* redm = (float*)&lds[0][0][0];   // [4 wc][256 tok]
  float* reds = redm + 4 * 256;

#pragma unroll
  for (int f = 0; f < 8; ++f) {
    float m = acc[f][0][0];
#pragma unroll
    for (int j = 0; j < 4; ++j)
#pragma unroll
      for (int r = 0; r < 4; ++r) m = fmaxf(m, acc[f][j][r]);
    float s = 0.f;
#pragma unroll
    for (int j = 0; j < 4; ++j)
#pragma unroll
      for (int r = 0; r < 4; ++r) s += __expf(acc[f][j][r] - m);
#pragma unroll
    for (int st = 16; st <= 32; st <<= 1) {
      float om = __shfl_xor(m, st, 64);
      float os = __shfl_xor(s, st, 64);
      float nm = fmaxf(m, om);
      s = s * __expf(m - nm) + os * __expf(om - nm);
      m = nm;
    }
    if (quad == 0) {
      int tok = wr * 128 + f * 16 + lc;
      redm[wc * 256 + tok] = m;
      reds[wc * 256 + tok] = s;
    }
  }
  __syncthreads();
  if (tid < 256) {
    float M = redm[tid], S = reds[tid];
#pragma unroll
    for (int w = 1; w < 4; ++w) {
      float m2 = redm[w * 256 + tid], s2 = reds[w * 256 + tid];
      float nm = fmaxf(M, m2);
      S = S * __expf(M - nm) + s2 * __expf(m2 - nm);
      M = nm;
    }
    Pp[(size_t)blockIdx.y * kTok + m_base + tid] = make_float2(M, S);
  }
}

// Exact fp32 selected-logit from the ORIGINAL fp32 inputs.
__global__ __launch_bounds__(256) void sel_kernel(
    const float* __restrict__ X0, const float* __restrict__ W0,
    const float* __restrict__ X1, const float* __restrict__ W1,
    const int* __restrict__ ids, float* __restrict__ sel0, float* __restrict__ sel1)
{
  const int model = blockIdx.y;
  const float* X = model ? X1 : X0;
  const float* W = model ? W1 : W0;
  float* out = model ? sel1 : sel0;
  const int wave = threadIdx.x >> 6, lane = threadIdx.x & 63;
  const int t  = blockIdx.x * 4 + wave;
  const int id = ids[t];
  const float* xr = X + (size_t)t * kH;
  const float* wr = W + (size_t)id * kH;
  float s = 0.f;
#pragma unroll
  for (int r = 0; r < 4; ++r) {
    int idx = r * 256 + lane * 4;
    float4 a = *(const float4*)&xr[idx];
    float4 b = *(const float4*)&wr[idx];
    s += a.x * b.x + a.y * b.y + a.z * b.z + a.w * b.w;
  }
#pragma unroll
  for (int st = 32; st; st >>= 1) s += __shfl_xor(s, st, 64);
  if (lane == 0) out[t] = s;
}

// Combine 125 partials/model -> lse; GRPO loss; reduce.
__global__ __launch_bounds__(256) void finalize_kernel(
    const float2* __restrict__ P0, const float2* __restrict__ P1,
    const float* __restrict__ sel0, const float* __restrict__ sel1,
    const float* __restrict__ adv, const int* __restrict__ mask,
    float* __restrict__ accum)
{
  const int t = blockIdx.x * 256 + threadIdx.x;
  float M0 = -INFINITY, S0 = 0.f, M1 = -INFINITY, S1 = 0.f;
  for (int i = 0; i < NVT; ++i) {
    float2 p = P0[(size_t)i * kTok + t];
    if (p.x > M0) { S0 = S0 * __expf(M0 - p.x) + p.y; M0 = p.x; }
    else          { S0 += p.y * __expf(p.x - M0); }
  }
  for (int i = 0; i < NVT; ++i) {
    float2 p = P1[(size_t)i * kTok + t];
    if (p.x > M1) { S1 = S1 * __expf(M1 - p.x) + p.y; M1 = p.x; }
    else          { S1 += p.y * __expf(p.x - M1); }
  }
  float lse0  = M0 + logf(S0);
  float lse1  = M1 + logf(S1);
  float logp  = sel0[t] - lse0;
  float rlogp = sel1[t] - lse1;
  float d  = rlogp - logp;
  float kl = __expf(d) - d - 1.f;
  // coef_1 = exp(logp - stopgrad(logp)) == 1, clip == 1 -> loss = -adv + beta*kl
  float a  = adv[t >> 10];
  float mv = (float)mask[t];
  float loss = (-a + 0.1f * kl) * mv;

#pragma unroll
  for (int st = 32; st; st >>= 1) {
    loss += __shfl_xor(loss, st, 64);
    mv   += __shfl_xor(mv, st, 64);
  }
  __shared__ float lsum[4], msum[4];
  const int wave = threadIdx.x >> 6, lane = threadIdx.x & 63;
  if (lane == 0) { lsum[wave] = loss; msum[wave] = mv; }
  __syncthreads();
  if (threadIdx.x == 0) {
    atomicAdd(&accum[0], lsum[0] + lsum[1] + lsum[2] + lsum[3]);
    atomicAdd(&accum[1], msum[0] + msum[1] + msum[2] + msum[3]);
  }
}

__global__ void scalar_kernel(const float* __restrict__ accum, float* __restrict__ out)
{
  out[0] = accum[0] / fmaxf(accum[1], 1.f);
}

extern "C" void kernel_launch(void* const* d_in, const int* in_sizes, int n_in,
                              void* d_out, int out_size, void* d_ws, size_t ws_size,
                              hipStream_t stream)
{
  const float* x    = (const float*)d_in[0];
  const float* w    = (const float*)d_in[1];
  const float* rx   = (const float*)d_in[2];
  const float* rw   = (const float*)d_in[3];
  const float* adv  = (const float*)d_in[4];
  const int*   ids  = (const int*)d_in[5];
  const int*   mask = (const int*)d_in[6];
  float* out = (float*)d_out;

  // Workspace layout (~152 MB): f16 copies + partials + sel + accum.
  char* ws = (char*)d_ws;
  _Float16* Xh  = (_Float16*)ws;                         // 8 MB
  _Float16* Wh  = Xh + (size_t)kTok * kH;                // 64 MB
  _Float16* RXh = Wh + (size_t)kV * kH;                  // 8 MB
  _Float16* RWh = RXh + (size_t)kTok * kH;               // 64 MB
  float2*   P0  = (float2*)(RWh + (size_t)kV * kH);      // 4 MB
  float2*   P1  = P0 + (size_t)NVT * kTok;               // 4 MB
  float*    sel0 = (float*)(P1 + (size_t)NVT * kTok);
  float*    sel1 = sel0 + kTok;
  float*    accum = sel1 + kTok;

  hipMemsetAsync(accum, 0, 2 * sizeof(float), stream);

  convert_kernel<<<kTok * 128 / 256, 256, 0, stream>>>(x,  Xh);
  convert_kernel<<<kV   * 128 / 256, 256, 0, stream>>>(w,  Wh);
  convert_kernel<<<kTok * 128 / 256, 256, 0, stream>>>(rx, RXh);
  convert_kernel<<<kV   * 128 / 256, 256, 0, stream>>>(rw, RWh);

  sel_kernel<<<dim3(kTok / 4, 2), 256, 0, stream>>>(x, w, rx, rw, ids, sel0, sel1);

  lse_gemm_kernel<<<dim3(NMT, NVT, 2), 512, 0, stream>>>(Xh, Wh, RXh, RWh, P0, P1);

  finalize_kernel<<<kTok / 256, 256, 0, stream>>>(P0, P1, sel0, sel1, adv, mask, accum);
  scalar_kernel<<<1, 1, 0, stream>>>(accum, out);
}